// Round 2
// baseline (1457.101 us; speedup 1.0000x reference)
//
#include <hip/hip_runtime.h>

// Graph unpooling scatter-add: out[dst[e], :] += edge_attr[e] * x[src[e], :]
// Baseline: one 32-lane group per edge, float4 per lane (128 ch = 32 * float4),
// 4x f32 global atomicAdd per lane. Atomic contention is low (avg degree 4,
// random dst). x (25.6 MB) lives in L3 so gathered reads are cache hits.
// [Round 1: unchanged resubmit — round 0 bench died on GPU acquisition timeout]

__global__ __launch_bounds__(256) void unpool_scatter_atomic(
    const float* __restrict__ x,
    const int* __restrict__ src_idx,
    const int* __restrict__ dst_idx,
    const float* __restrict__ edge_attr,
    float* __restrict__ out,
    int E)
{
    long tid = (long)blockIdx.x * (long)blockDim.x + threadIdx.x;
    int e = (int)(tid >> 5);          // edge index
    if (e >= E) return;
    int q = (int)(tid & 31);          // which float4 of the 128-ch row

    int src = src_idx[e];
    int dst = dst_idx[e];
    float w = edge_attr[e];

    const float4 v = reinterpret_cast<const float4*>(x)[((long)src << 5) + q];
    float* o = out + ((long)dst << 7) + (q << 2);

    atomicAdd(o + 0, v.x * w);
    atomicAdd(o + 1, v.y * w);
    atomicAdd(o + 2, v.z * w);
    atomicAdd(o + 3, v.w * w);
}

extern "C" void kernel_launch(void* const* d_in, const int* in_sizes, int n_in,
                              void* d_out, int out_size, void* d_ws, size_t ws_size,
                              hipStream_t stream) {
    const float* x        = (const float*)d_in[0];
    const int*   src_idx  = (const int*)d_in[1];
    const int*   dst_idx  = (const int*)d_in[2];
    const float* edge_att = (const float*)d_in[3];
    float*       out      = (float*)d_out;

    const int E = in_sizes[1];        // 800000 edges

    // d_out is poisoned 0xAA before every timed call — must zero it.
    hipMemsetAsync(d_out, 0, (size_t)out_size * sizeof(float), stream);

    const long total_threads = (long)E * 32;
    const int  block = 256;
    const long grid = (total_threads + block - 1) / block;

    unpool_scatter_atomic<<<dim3((unsigned)grid), dim3(block), 0, stream>>>(
        x, src_idx, dst_idx, edge_att, out, E);
}

// Round 3
// 276.744 us; speedup vs baseline: 5.2652x; 5.2652x over previous
//
#include <hip/hip_runtime.h>

// Graph unpooling: out[dst[e], :] += edge_attr[e] * x[src[e], :]
// Strategy: no value-atomics. Build reverse CSR (dst -> edge list) on device
// every call, then one accumulate kernel: 32-lane group per output row,
// register accumulation, single streaming float4 store per lane.
// R2 baseline (pure atomicAdd): 1342 us, WRITE_SIZE 1.6 GB (16x amplification
// from random scatter thrashing L2). Compulsory traffic ~138 MB -> ~22 us floor.

#define SCAN_TILE 2048  // elements per scan1 tile (256 thr x 8)

// --- CSR build ---------------------------------------------------------------

__global__ __launch_bounds__(256) void k_hist(
    const int* __restrict__ dst, int* __restrict__ counts, int E)
{
    int e = blockIdx.x * 256 + threadIdx.x;
    if (e < E) atomicAdd(&counts[dst[e]], 1);
}

// Per-tile exclusive scan; tile totals to bsums.
__global__ __launch_bounds__(256) void k_scan1(
    const int* __restrict__ counts, int* __restrict__ excl,
    int* __restrict__ bsums, int N)
{
    __shared__ int lds[256];
    int t = threadIdx.x;
    int base = blockIdx.x * SCAN_TILE + t * 8;
    int v[8];
    int s = 0;
    #pragma unroll
    for (int k = 0; k < 8; ++k) {
        int i = base + k;
        v[k] = (i < N) ? counts[i] : 0;
        s += v[k];
    }
    // Hillis-Steele inclusive scan of the 256 per-thread sums.
    int val = s;
    lds[t] = val;
    __syncthreads();
    for (int off = 1; off < 256; off <<= 1) {
        int add = (t >= off) ? lds[t - off] : 0;
        __syncthreads();
        val += add;
        lds[t] = val;
        __syncthreads();
    }
    if (t == 255) bsums[blockIdx.x] = val;     // tile total
    int run = val - s;                          // exclusive prefix of thread
    #pragma unroll
    for (int k = 0; k < 8; ++k) {
        int i = base + k;
        if (i < N) excl[i] = run;
        run += v[k];
    }
}

// Exclusive scan of tile totals (nb <= 128) in one block.
__global__ __launch_bounds__(128) void k_scan2(int* __restrict__ bsums, int nb)
{
    __shared__ int lds[128];
    int t = threadIdx.x;
    int v = (t < nb) ? bsums[t] : 0;
    int val = v;
    lds[t] = val;
    __syncthreads();
    for (int off = 1; off < 128; off <<= 1) {
        int add = (t >= off) ? lds[t - off] : 0;
        __syncthreads();
        val += add;
        lds[t] = val;
        __syncthreads();
    }
    if (t < nb) bsums[t] = val - v;             // exclusive
}

// Add tile offsets; also initialize the fill cursors.
__global__ __launch_bounds__(256) void k_scan3(
    int* __restrict__ excl, int* __restrict__ cursors,
    const int* __restrict__ bsums, int N)
{
    int i = blockIdx.x * 256 + threadIdx.x;
    if (i < N) {
        int v = excl[i] + bsums[i >> 11];       // i / SCAN_TILE
        excl[i] = v;
        cursors[i] = v;
    }
}

// Scatter edges into CSR slots: pairs[pos] = (src, w).
__global__ __launch_bounds__(256) void k_fill(
    const int* __restrict__ src, const int* __restrict__ dst,
    const float* __restrict__ w, int* __restrict__ cursors,
    int2* __restrict__ pairs, int E)
{
    int e = blockIdx.x * 256 + threadIdx.x;
    if (e < E) {
        int d = dst[e];
        int pos = atomicAdd(&cursors[d], 1);
        pairs[pos] = make_int2(src[e], __float_as_int(w[e]));
    }
}

// --- Accumulate: 32-lane group per output row -------------------------------

__global__ __launch_bounds__(256) void k_accum(
    const float* __restrict__ x, const int* __restrict__ offsets,
    const int* __restrict__ counts, const int2* __restrict__ pairs,
    float* __restrict__ out, int N)
{
    long tid = (long)blockIdx.x * 256 + threadIdx.x;
    int row = (int)(tid >> 5);
    if (row >= N) return;
    int q = (int)(tid & 31);

    int start = offsets[row];
    int cnt   = counts[row];

    const float4* x4 = reinterpret_cast<const float4*>(x);
    float4 acc = {0.f, 0.f, 0.f, 0.f};
    for (int j = 0; j < cnt; ++j) {
        int2 p = pairs[start + j];              // broadcast across 32 lanes
        float w = __int_as_float(p.y);
        float4 v = x4[((long)p.x << 5) + q];    // coalesced 512B per group
        acc.x += w * v.x; acc.y += w * v.y;
        acc.z += w * v.z; acc.w += w * v.w;
    }
    reinterpret_cast<float4*>(out)[((long)row << 5) + q] = acc;  // rows with
    // cnt==0 store zeros -> no separate d_out memset needed.
}

// --- Fallback (ws too small): R2 atomic baseline ----------------------------

__global__ __launch_bounds__(256) void unpool_scatter_atomic(
    const float* __restrict__ x, const int* __restrict__ src_idx,
    const int* __restrict__ dst_idx, const float* __restrict__ edge_attr,
    float* __restrict__ out, int E)
{
    long tid = (long)blockIdx.x * (long)blockDim.x + threadIdx.x;
    int e = (int)(tid >> 5);
    if (e >= E) return;
    int q = (int)(tid & 31);
    int src = src_idx[e];
    int dst = dst_idx[e];
    float w = edge_attr[e];
    const float4 v = reinterpret_cast<const float4*>(x)[((long)src << 5) + q];
    float* o = out + ((long)dst << 7) + (q << 2);
    atomicAdd(o + 0, v.x * w);
    atomicAdd(o + 1, v.y * w);
    atomicAdd(o + 2, v.z * w);
    atomicAdd(o + 3, v.w * w);
}

extern "C" void kernel_launch(void* const* d_in, const int* in_sizes, int n_in,
                              void* d_out, int out_size, void* d_ws, size_t ws_size,
                              hipStream_t stream) {
    const float* x        = (const float*)d_in[0];
    const int*   src_idx  = (const int*)d_in[1];
    const int*   dst_idx  = (const int*)d_in[2];
    const float* edge_att = (const float*)d_in[3];
    float*       out      = (float*)d_out;

    const int E = in_sizes[1];          // 800000
    const int C = 128;
    const int N = out_size / C;         // n_fine = 200000
    const int NB = (N + SCAN_TILE - 1) / SCAN_TILE;   // scan tiles (98)

    // ws layout (all 4B-aligned; pairs needs 8B)
    size_t off_counts  = 0;
    size_t off_offsets = off_counts  + (size_t)N * 4;
    size_t off_cursors = off_offsets + (size_t)N * 4;
    size_t off_bsums   = off_cursors + (size_t)N * 4;
    size_t off_pairs   = (off_bsums + (size_t)NB * 4 + 7) & ~(size_t)7;
    size_t need        = off_pairs + (size_t)E * 8;

    if (ws_size < need || NB > 128) {
        // Fallback: atomic baseline.
        hipMemsetAsync(d_out, 0, (size_t)out_size * sizeof(float), stream);
        long total = (long)E * 32;
        unpool_scatter_atomic<<<dim3((unsigned)((total + 255) / 256)), dim3(256),
                                0, stream>>>(x, src_idx, dst_idx, edge_att, out, E);
        return;
    }

    char* ws = (char*)d_ws;
    int*  counts  = (int*)(ws + off_counts);
    int*  offsets = (int*)(ws + off_offsets);
    int*  cursors = (int*)(ws + off_cursors);
    int*  bsums   = (int*)(ws + off_bsums);
    int2* pairs   = (int2*)(ws + off_pairs);

    hipMemsetAsync(counts, 0, (size_t)N * 4, stream);

    k_hist <<<dim3((E + 255) / 256), dim3(256), 0, stream>>>(dst_idx, counts, E);
    k_scan1<<<dim3(NB),             dim3(256), 0, stream>>>(counts, offsets, bsums, N);
    k_scan2<<<dim3(1),              dim3(128), 0, stream>>>(bsums, NB);
    k_scan3<<<dim3((N + 255) / 256), dim3(256), 0, stream>>>(offsets, cursors, bsums, N);
    k_fill <<<dim3((E + 255) / 256), dim3(256), 0, stream>>>(src_idx, dst_idx,
                                                             edge_att, cursors, pairs, E);

    long total = (long)N * 32;
    k_accum<<<dim3((unsigned)((total + 255) / 256)), dim3(256), 0, stream>>>(
        x, offsets, counts, pairs, out, N);
}

// Round 4
// 264.536 us; speedup vs baseline: 5.5081x; 1.0461x over previous
//
#include <hip/hip_runtime.h>

// Graph unpooling: out[dst[e], :] += edge_attr[e] * x[src[e], :]
// R4: fixed-capacity bucket CSR (no scan). k_scatter fuses rank+place:
//   r = atomicAdd(counts[d]); r<CAP -> pairs[d*CAP+r]; else overflow list.
// k_accum: 32 lanes/row, loads all CAP slots (int4), issues all gathers as
// independent predicated loads (breaks the serial load->load chain of R3),
// one streaming float4 store per lane. Overflow edges atomicAdd'ed after.
// History: R2 atomics 1342us (WRITE 1.6GB); R3 full-CSR 277us total
// (k_accum 83us, CSR build ~190us across 6 dispatches).

template<int CAP>
__global__ __launch_bounds__(256) void k_scatter(
    const int* __restrict__ src, const int* __restrict__ dst,
    const float* __restrict__ w,
    int* __restrict__ counts, int* __restrict__ ovf_cnt,
    int* __restrict__ ovf_idx, int2* __restrict__ pairs, int E)
{
    int e = blockIdx.x * 256 + threadIdx.x;
    if (e >= E) return;
    int d = dst[e];
    int r = atomicAdd(&counts[d], 1);
    if (r < CAP) {
        pairs[(size_t)d * CAP + r] = make_int2(src[e], __float_as_int(w[e]));
    } else {
        int p = atomicAdd(ovf_cnt, 1);
        ovf_idx[p] = e;
    }
}

template<int CAP>
__global__ __launch_bounds__(256) void k_accum(
    const float* __restrict__ x, const int* __restrict__ counts,
    const int2* __restrict__ pairs, float* __restrict__ out, int N)
{
    long tid = (long)blockIdx.x * 256 + threadIdx.x;
    int row = (int)(tid >> 5);
    if (row >= N) return;
    int q = (int)(tid & 31);

    int cnt = counts[row];
    if (cnt > CAP) cnt = CAP;

    // Load all CAP slots (row-contiguous, 16B-aligned).
    const int4* prow = reinterpret_cast<const int4*>(pairs + (size_t)row * CAP);
    int s[CAP]; float wv[CAP];
    #pragma unroll
    for (int r2 = 0; r2 < CAP / 2; ++r2) {
        int4 pk = prow[r2];
        s[2 * r2]     = pk.x; wv[2 * r2]     = __int_as_float(pk.y);
        s[2 * r2 + 1] = pk.z; wv[2 * r2 + 1] = __int_as_float(pk.w);
    }
    #pragma unroll
    for (int r = 0; r < CAP; ++r)
        if (r >= cnt) wv[r] = 0.f;           // sanitize poison slots

    // Independent predicated gathers -> all in flight before accumulation.
    const float4* x4 = reinterpret_cast<const float4*>(x);
    float4 v[CAP];
    #pragma unroll
    for (int r = 0; r < CAP; ++r) {
        v[r] = make_float4(0.f, 0.f, 0.f, 0.f);
        if (r < cnt) v[r] = x4[((long)s[r] << 5) + q];
    }
    float4 acc = make_float4(0.f, 0.f, 0.f, 0.f);
    #pragma unroll
    for (int r = 0; r < CAP; ++r) {
        acc.x += wv[r] * v[r].x; acc.y += wv[r] * v[r].y;
        acc.z += wv[r] * v[r].z; acc.w += wv[r] * v[r].w;
    }
    reinterpret_cast<float4*>(out)[((long)row << 5) + q] = acc;
}

// Runs AFTER k_accum's stores; adds the rare rank>=CAP edges.
__global__ __launch_bounds__(256) void k_overflow(
    const float* __restrict__ x, const int* __restrict__ src,
    const int* __restrict__ dst, const float* __restrict__ w,
    const int* __restrict__ ovf_cnt, const int* __restrict__ ovf_idx,
    float* __restrict__ out)
{
    int novf = *ovf_cnt;
    long total = (long)novf * 32;
    long stride = (long)gridDim.x * 256;
    for (long i = (long)blockIdx.x * 256 + threadIdx.x; i < total; i += stride) {
        int k = (int)(i >> 5);
        int q = (int)(i & 31);
        int e = ovf_idx[k];
        float ww = w[e];
        float4 v = reinterpret_cast<const float4*>(x)[((long)src[e] << 5) + q];
        float* o = out + ((long)dst[e] << 7) + (q << 2);
        atomicAdd(o + 0, v.x * ww); atomicAdd(o + 1, v.y * ww);
        atomicAdd(o + 2, v.z * ww); atomicAdd(o + 3, v.w * ww);
    }
}

// Fallback: R2 atomic baseline (only if ws is tiny).
__global__ __launch_bounds__(256) void unpool_scatter_atomic(
    const float* __restrict__ x, const int* __restrict__ src_idx,
    const int* __restrict__ dst_idx, const float* __restrict__ edge_attr,
    float* __restrict__ out, int E)
{
    long tid = (long)blockIdx.x * (long)blockDim.x + threadIdx.x;
    int e = (int)(tid >> 5);
    if (e >= E) return;
    int q = (int)(tid & 31);
    float w = edge_attr[e];
    const float4 v = reinterpret_cast<const float4*>(x)[((long)src_idx[e] << 5) + q];
    float* o = out + ((long)dst_idx[e] << 7) + (q << 2);
    atomicAdd(o + 0, v.x * w); atomicAdd(o + 1, v.y * w);
    atomicAdd(o + 2, v.z * w); atomicAdd(o + 3, v.w * w);
}

template<int CAP>
static void launch_bucket_path(const float* x, const int* src_idx,
                               const int* dst_idx, const float* edge_att,
                               float* out, char* ws, int E, int N,
                               size_t off_ovf, size_t off_ovfidx, size_t off_pairs,
                               hipStream_t stream)
{
    int*  counts  = (int*)(ws);
    int*  ovf_cnt = (int*)(ws + off_ovf);
    int*  ovf_idx = (int*)(ws + off_ovfidx);
    int2* pairs   = (int2*)(ws + off_pairs);

    // Zero counts + overflow counter in one memset.
    hipMemsetAsync(ws, 0, off_ovf + 16, stream);

    k_scatter<CAP><<<dim3((E + 255) / 256), dim3(256), 0, stream>>>(
        src_idx, dst_idx, edge_att, counts, ovf_cnt, ovf_idx, pairs, E);

    long total = (long)N * 32;
    k_accum<CAP><<<dim3((unsigned)((total + 255) / 256)), dim3(256), 0, stream>>>(
        x, counts, pairs, out, N);

    k_overflow<<<dim3(1024), dim3(256), 0, stream>>>(
        x, src_idx, dst_idx, edge_att, ovf_cnt, ovf_idx, out);
}

extern "C" void kernel_launch(void* const* d_in, const int* in_sizes, int n_in,
                              void* d_out, int out_size, void* d_ws, size_t ws_size,
                              hipStream_t stream) {
    const float* x        = (const float*)d_in[0];
    const int*   src_idx  = (const int*)d_in[1];
    const int*   dst_idx  = (const int*)d_in[2];
    const float* edge_att = (const float*)d_in[3];
    float*       out      = (float*)d_out;

    const int E = in_sizes[1];          // 800000
    const int C = 128;
    const int N = out_size / C;         // 200000

    size_t off_ovf    = ((size_t)N * 4 + 15) & ~(size_t)15;   // counts end, 16B-aligned
    size_t off_ovfidx = off_ovf + 16;
    size_t off_pairs  = (off_ovfidx + (size_t)E * 4 + 15) & ~(size_t)15;
    size_t need8 = off_pairs + (size_t)N * 8 * 8;
    size_t need4 = off_pairs + (size_t)N * 4 * 8;

    char* ws = (char*)d_ws;
    if (ws_size >= need8) {
        launch_bucket_path<8>(x, src_idx, dst_idx, edge_att, out, ws, E, N,
                              off_ovf, off_ovfidx, off_pairs, stream);
    } else if (ws_size >= need4) {
        launch_bucket_path<4>(x, src_idx, dst_idx, edge_att, out, ws, E, N,
                              off_ovf, off_ovfidx, off_pairs, stream);
    } else {
        hipMemsetAsync(d_out, 0, (size_t)out_size * sizeof(float), stream);
        long total = (long)E * 32;
        unpool_scatter_atomic<<<dim3((unsigned)((total + 255) / 256)), dim3(256),
                                0, stream>>>(x, src_idx, dst_idx, edge_att, out, E);
    }
}